// Round 8
// baseline (1849.270 us; speedup 1.0000x reference)
//
#include <hip/hip_runtime.h>

typedef unsigned short u16;
typedef unsigned long long u64;
typedef __attribute__((ext_vector_type(8))) short bf16x8;
typedef __attribute__((ext_vector_type(4))) float f32x4;
typedef __attribute__((ext_vector_type(4))) unsigned short us4;

#define MFMA(a,b,c) __builtin_amdgcn_mfma_f32_16x16x32_bf16((a),(b),(c),0,0,0)
#define KEEP(x) asm volatile("" : "+v"(x))

// B=128, SEQ=200, VOCAB=1400 (pad 1408), D=H=256, 4H=1024, NCLS=128, M=B*SEQ=25600

static __device__ __forceinline__ u16 f2b(float f){
  unsigned u = __float_as_uint(f);
  u += 0x7fffu + ((u >> 16) & 1u);          // RNE fp32 -> bf16
  return (u16)(u >> 16);
}
static __device__ __forceinline__ float b2f(u16 v){
  return __uint_as_float(((unsigned)v) << 16);
}
static __device__ __forceinline__ float sigm(float x){ return 1.0f/(1.0f+__expf(-x)); }
static __device__ __forceinline__ float tanhx(float x){
  x = fminf(fmaxf(x, -15.f), 15.f);
  float e = __expf(-2.f*x);
  return (1.f - e)/(1.f + e);
}
static __device__ __forceinline__ void gl16(const void* g, void* l){
  __builtin_amdgcn_global_load_lds((const __attribute__((address_space(1))) void*)g,
                                   (__attribute__((address_space(3))) void*)l, 16, 0, 0);
}

// ---------------- fused prep: inputs cvt + emb transpose-cvt + weights ----
__global__ __launch_bounds__(256) void k_prep(
  const float* __restrict__ in0, u16* __restrict__ A0,
  const float* __restrict__ emb, u16* __restrict__ embT,
  const float* __restrict__ s0, const float* __restrict__ s1, const float* __restrict__ s2,
  const float* __restrict__ s3, const float* __restrict__ s4, const float* __restrict__ s5,
  const float* __restrict__ s6,
  u16* __restrict__ d0, u16* __restrict__ d1, u16* __restrict__ d2, u16* __restrict__ d3,
  u16* __restrict__ d4, u16* __restrict__ d5, u16* __restrict__ d6)
{
  int bx = blockIdx.x, tid = threadIdx.x;
  if (bx < 35200){                     // inputs [25600 x 1400] -> bf16 padded 1408
    long long i4 = (long long)bx*256 + tid;      // < 9011200 exactly
    long long o = i4*4;
    int r = (int)(o / 1408);
    int c = (int)(o % 1408);
    us4 d;
    if (c + 4 <= 1400){
      f32x4 v = *(const f32x4*)&in0[(long long)r*1400 + c];
      d[0]=f2b(v[0]); d[1]=f2b(v[1]); d[2]=f2b(v[2]); d[3]=f2b(v[3]);
    } else {
      for (int k=0;k<4;k++){ int cc=c+k; d[k] = (cc<1400)? f2b(in0[(long long)r*1400+cc]) : (u16)0; }
    }
    *(us4*)&A0[(long long)r*1408 + c] = d;
  } else if (bx < 36608){              // emb [1400x256] -> embT [256x1408] bf16
    int idx = (bx-35200)*256 + tid;    // < 360448 exactly
    int n = idx / 1408, k = idx % 1408;
    embT[idx] = (k < 1400) ? f2b(emb[(long long)k*256 + n]) : (u16)0;
  } else {                             // 7 weight arrays fp32 -> bf16
    long long q = (long long)(bx-36608)*256 + tid;   // < 311296 exactly
    const float* src; u16* dst; long long rel;
    if      (q < 65536)  { src=s0; dst=d0; rel=q; }
    else if (q < 131072) { src=s1; dst=d1; rel=q-65536; }
    else if (q < 196608) { src=s2; dst=d2; rel=q-131072; }
    else if (q < 262144) { src=s3; dst=d3; rel=q-196608; }
    else if (q < 278528) { src=s4; dst=d4; rel=q-262144; }
    else if (q < 294912) { src=s5; dst=d5; rel=q-278528; }
    else                 { src=s6; dst=d6; rel=q-294912; }
    long long o = rel*4;
    f32x4 v = *(const f32x4*)&src[o];
    us4 d; d[0]=f2b(v[0]); d[1]=f2b(v[1]); d[2]=f2b(v[2]); d[3]=f2b(v[3]);
    *(us4*)&dst[o] = d;
  }
}

// ---------------- init: zero E + ctx ----------------
__global__ __launch_bounds__(256) void k_init(float* __restrict__ E, float* __restrict__ ctx){
  int i = blockIdx.x*256 + threadIdx.x;     // 256*256 = 65536 exactly
  if (i < 32768) E[i] = 0.f;
  else ctx[i-32768] = 0.f;
}

// ---------------- bf16 MFMA GEMM: C[M,N] = A[M,K] * Bt[N,K]^T -------------
// EPI 1: write fp32 + bf16 copies
// EPI 6: dual bf16 ux output, +bias pair (blockIdx.y>=8 -> second set)
// EPI 5: ctx[b,col] += emb[row,col]*tanh(acc)*alpha[row]  (LDS + global atomics)
template<int EPI>
__global__ __launch_bounds__(256) void k_gemm(const u16* __restrict__ A, const u16* __restrict__ Bt,
    int N, int K,
    float* __restrict__ Cf, u16* __restrict__ Cb,
    const float* __restrict__ bias1, const float* __restrict__ bias2,
    const u16* __restrict__ Bt2, u16* __restrict__ Cb2,
    const float* __restrict__ bias3, const float* __restrict__ bias4,
    const float* __restrict__ emb, const float* __restrict__ alpha)
{
  __shared__ __align__(16) u16 As[128*64];
  __shared__ __align__(16) u16 Bs[128*64];
  __shared__ float red[2][128];
  const int tid = threadIdx.x;
  const int l = tid & 63, w = tid >> 6;
  const int quad = l >> 4, lb = l & 15;
  const int wr = w >> 1, wc = w & 1;
  const long long m0 = (long long)blockIdx.x * 128;
  int n0 = blockIdx.y * 128;
  if (EPI==6 && blockIdx.y >= 8){
    Bt = Bt2; Cb = Cb2; bias1 = bias3; bias2 = bias4; n0 = (blockIdx.y-8)*128;
  }

  f32x4 acc[4][4];
  #pragma unroll
  for (int i=0;i<4;i++)
    #pragma unroll
    for (int j=0;j<4;j++) acc[i][j] = (f32x4){0.f,0.f,0.f,0.f};

  for (int kk = 0; kk < K; kk += 64){
    #pragma unroll
    for (int it=0; it<4; ++it){      // 128x64 bf16 tile, XOR-swizzled 16B slots
      int slot = it*256 + tid;
      int m = slot >> 3;
      int q = (slot & 7) ^ (m & 7);
      gl16(A + (m0+m)*K + kk + q*8, &As[slot*8]);
    }
    #pragma unroll
    for (int it=0; it<4; ++it){
      int slot = it*256 + tid;
      int m = slot >> 3;
      int q = (slot & 7) ^ (m & 7);
      gl16(Bt + (long long)(n0+m)*K + kk + q*8, &Bs[slot*8]);
    }
    __syncthreads();
    #pragma unroll
    for (int ks=0; ks<2; ++ks){
      int kq = quad + ks*4;
      bf16x8 af[4], bfr[4];
      #pragma unroll
      for (int i=0;i<4;i++){ int m = wr*64 + i*16 + lb; af[i]  = *(const bf16x8*)&As[m*64 + ((kq ^ (m&7))*8)]; }
      #pragma unroll
      for (int j=0;j<4;j++){ int n = wc*64 + j*16 + lb; bfr[j] = *(const bf16x8*)&Bs[n*64 + ((kq ^ (n&7))*8)]; }
      #pragma unroll
      for (int i=0;i<4;i++)
        #pragma unroll
        for (int j=0;j<4;j++)
          acc[i][j] = MFMA(af[i], bfr[j], acc[i][j]);
    }
    __syncthreads();
  }

  if (EPI==5){
    const int b0 = (int)(m0 / 200);
    red[tid>>7][tid&127] = 0.f;
    __syncthreads();
    #pragma unroll
    for (int i=0;i<4;i++){
      #pragma unroll
      for (int j=0;j<4;j++){
        int col = wc*64 + j*16 + lb;          // 0..127 within n0 tile
        #pragma unroll
        for (int r=0;r<4;r++){
          long long row = m0 + wr*64 + i*16 + quad*4 + r;
          long long o = row*N + n0 + col;
          float v = emb[o] * tanhx(acc[i][j][r]) * alpha[row];
          atomicAdd(&red[(int)(row/200) - b0][col], v);
        }
      }
    }
    __syncthreads();
    int bl = tid >> 7, col = tid & 127;       // 256 threads cover [2][128]
    int bb = b0 + bl;
    if (bb < 128) atomicAdd(&Cf[bb*256 + n0 + col], red[bl][col]);
    return;
  }

  #pragma unroll
  for (int i=0;i<4;i++){
    #pragma unroll
    for (int j=0;j<4;j++){
      int col = n0 + wc*64 + j*16 + lb;
      #pragma unroll
      for (int r=0;r<4;r++){
        long long row = m0 + wr*64 + i*16 + quad*4 + r;
        long long o = row*N + col;
        float v = acc[i][j][r];
        if (EPI==1){ Cf[o]=v; Cb[o]=f2b(v); }
        else if (EPI==6){ Cb[o] = f2b(v + bias1[col] + bias2[col]); }
      }
    }
  }
}

// ---------------- persistent TimeLSTM scan (2-chunk pipelined exchange) ---
// 32 WGs: bi>>4 = lstm, (bi>>2)&3 = batch PAIR, bi&3 = j-chunk of 64.
// Each WG runs TWO independent 16-batch chains (A = pair*2, B = pair*2+1)
// with the same register-resident weights. Pipeline: compute+publish A,
// compute+publish B (B's compute touches no vmem, so A/B publish stores
// drain to the MALL in its shadow), then poll A, poll B (B's flight hides
// under A's unpack). Tagged-payload protocol as R7: each u64 = 3 data u16 +
// 16-bit step tag; one MALL RT delivers validity+payload; 2 slots per chunk
// namespace; reading tag-t is a prerequisite of publishing t+1.
__global__ __launch_bounds__(256,1) void k_scan(
  const u16* __restrict__ Wall1, const u16* __restrict__ Wd1, const float* __restrict__ Wd1b,
  const u16* __restrict__ ux1, const float* __restrict__ h01, const float* __restrict__ c01,
  const u16* __restrict__ Wall2, const u16* __restrict__ Wd2, const float* __restrict__ Wd2b,
  const u16* __restrict__ ux2, const float* __restrict__ h02, const float* __restrict__ c02,
  const float* __restrict__ ts, const float* __restrict__ wa,
  float* __restrict__ E, u16* __restrict__ out2,
  u64* __restrict__ pay)
{
  __shared__ __align__(16) u16 hbA[16][264];
  __shared__ __align__(16) u16 cbA[16][264];
  __shared__ __align__(16) u16 hbB[16][264];
  __shared__ __align__(16) u16 cbB[16][264];
  const int bi = blockIdx.x;           // 0..31
  const int lstm = bi >> 4;
  const int bp   = (bi >> 2) & 3;
  const int jw   = bi & 3;
  const int cA = bp*2, cB = bp*2+1;
  const int grpA = lstm*8 + cA;        // exchange namespaces (0..15)
  const int grpB = lstm*8 + cB;
  const u16* Wall  = lstm ? Wall2 : Wall1;
  const u16* Wd    = lstm ? Wd2   : Wd1;
  const float* Wdb = lstm ? Wd2b  : Wd1b;
  const u16* ux    = lstm ? ux2   : ux1;
  const float* h0  = lstm ? h02   : h01;
  const float* c0  = lstm ? c02   : c01;

  const int tid = threadIdx.x;
  const int l = tid & 63, w = tid >> 6;
  const int quad = l >> 4, lb = l & 15;
  const int bgA = cA*16 + lb;           // lane's global batch, chunk A
  const int bgB = cB*16 + lb;
  const int jwave = jw*64 + w*16;       // wave's 16 output rows (per gate)
  const int jlane = jwave + quad*4;     // lane's 4 j rows (C-layout)
  const int bb = tid >> 4, jj = tid & 15;   // refill role
  const bool sibR = (jj >> 2) != jw;        // refill from sibling WG?

  // ---- one-time: weight fragments into registers (A-frag: m=lb, k=quad*8+i)
  bf16x8 wfA[4][8], wdA[8];
  #pragma unroll
  for (int g=0; g<4; ++g)
    #pragma unroll
    for (int kk=0; kk<8; ++kk){
      wfA[g][kk] = *(const bf16x8*)&Wall[(long long)(g*256 + jwave + lb)*256 + kk*32 + quad*8];
      KEEP(wfA[g][kk]);
    }
  #pragma unroll
  for (int kk=0; kk<8; ++kk){
    wdA[kk] = *(const bf16x8*)&Wd[(long long)(jwave + lb)*256 + kk*32 + quad*8];
    KEEP(wdA[kk]);
  }

  f32x4 bcs  = *(const f32x4*)&Wdb[jlane];
  f32x4 wav  = *(const f32x4*)&wa[jlane];
  f32x4 cregA = *(const f32x4*)&c0[(long long)bgA*256 + jlane];
  f32x4 cregB = *(const f32x4*)&c0[(long long)bgB*256 + jlane];

  // ---- init LDS h/c for both chunks (full 256 j for 16 batches each)
  {
    int j0 = jj*16;
    #pragma unroll
    for (int kq=0; kq<4; ++kq){
      f32x4 hv = *(const f32x4*)&h0[(long long)(cA*16+bb)*256 + j0 + kq*4];
      f32x4 cv = *(const f32x4*)&c0[(long long)(cA*16+bb)*256 + j0 + kq*4];
      us4 hp0, cp0;
      #pragma unroll
      for (int r=0;r<4;++r){ hp0[r]=f2b(hv[r]); cp0[r]=f2b(cv[r]); }
      *(us4*)&hbA[bb][j0+kq*4] = hp0;
      *(us4*)&cbA[bb][j0+kq*4] = cp0;
      hv = *(const f32x4*)&h0[(long long)(cB*16+bb)*256 + j0 + kq*4];
      cv = *(const f32x4*)&c0[(long long)(cB*16+bb)*256 + j0 + kq*4];
      #pragma unroll
      for (int r=0;r<4;++r){ hp0[r]=f2b(hv[r]); cp0[r]=f2b(cv[r]); }
      *(us4*)&hbB[bb][j0+kq*4] = hp0;
      *(us4*)&cbB[bb][j0+kq*4] = cp0;
    }
  }
  __syncthreads();

  us4 uxrA[4], uxrB[4];
  #pragma unroll
  for (int g=0; g<4; ++g){
    uxrA[g] = *(const us4*)&ux[(long long)bgA*200*1024 + g*256 + jlane];
    uxrB[g] = *(const us4*)&ux[(long long)bgB*200*1024 + g*256 + jlane];
  }
  float tcurA = ts[(long long)bgA*200];
  float tcurB = ts[(long long)bgB*200];

  for (int s=0; s<200; ++s){
    const u64 tag = (u64)(s+1);
    const int slot = (s+1)&1;
    us4 hpA, cpA, hpB, cpB;
    // =========== chunk A compute + publish ===========
    {
      f32x4 ag[4];
      #pragma unroll
      for (int g=0; g<4; ++g)
        #pragma unroll
        for (int r=0; r<4; ++r) ag[g][r] = b2f(uxrA[g][r]);
      if (s < 199){
        #pragma unroll
        for (int g=0; g<4; ++g)
          uxrA[g] = *(const us4*)&ux[((long long)bgA*200 + s+1)*1024 + g*256 + jlane];
      }
      f32x4 ad = bcs;
      #pragma unroll
      for (int kk=0;kk<8;++kk){
        bf16x8 cf = *(const bf16x8*)&cbA[lb][kk*32 + quad*8];
        ad = MFMA(wdA[kk], cf, ad);
      }
      #pragma unroll
      for (int kk=0;kk<8;++kk){
        bf16x8 hf = *(const bf16x8*)&hbA[lb][kk*32 + quad*8];
        #pragma unroll
        for (int g=0; g<4; ++g) ag[g] = MFMA(wfA[g][kk], hf, ag[g]);
      }
      f32x4 hn;
      #pragma unroll
      for (int r=0;r<4;++r){
        float cs1 = tanhx(ad[r]);
        float cadj = cregA[r] + cs1*(tcurA - 1.0f);
        float fg = sigm(ag[0][r]);
        float ig = sigm(ag[1][r]);
        float og = sigm(ag[2][r]);
        float cg = sigm(ag[3][r]);
        float cn = fg*cadj + ig*cg;
        float hv = og*tanhx(cn);
        cregA[r]=cn; hn[r]=hv;
        hpA[r]=f2b(hv); cpA[r]=f2b(cn);
      }
      if (s < 199){
        tcurA = ts[(long long)bgA*200 + s+1];
        long long pw = ((((long long)(slot*16+grpA))*16 + lb)*64 + (jlane>>2))*3;
        u64 w0 = (u64)hpA[0] | ((u64)hpA[1]<<16) | ((u64)hpA[2]<<32) | (tag<<48);
        u64 w1 = (u64)hpA[3] | ((u64)cpA[0]<<16) | ((u64)cpA[1]<<32) | (tag<<48);
        u64 w2 = (u64)cpA[2] | ((u64)cpA[3]<<16) | (tag<<48);
        __hip_atomic_store(&pay[pw],   w0, __ATOMIC_RELAXED, __HIP_MEMORY_SCOPE_AGENT);
        __hip_atomic_store(&pay[pw+1], w1, __ATOMIC_RELAXED, __HIP_MEMORY_SCOPE_AGENT);
        __hip_atomic_store(&pay[pw+2], w2, __ATOMIC_RELAXED, __HIP_MEMORY_SCOPE_AGENT);
      }
      if (lstm==0){
        float e = hn[0]*wav[0] + hn[1]*wav[1] + hn[2]*wav[2] + hn[3]*wav[3];
        e += __shfl_xor(e, 16, 64);
        e += __shfl_xor(e, 32, 64);
        if (l < 16) atomicAdd(&E[(long long)bgA*256 + s], e);
      } else {
        *(us4*)&out2[((long long)bgA*200 + s)*256 + jlane] = hpA;
      }
    }
    // =========== chunk B compute + publish ===========
    {
      f32x4 ag[4];
      #pragma unroll
      for (int g=0; g<4; ++g)
        #pragma unroll
        for (int r=0; r<4; ++r) ag[g][r] = b2f(uxrB[g][r]);
      if (s < 199){
        #pragma unroll
        for (int g=0; g<4; ++g)
          uxrB[g] = *(const us4*)&ux[((long long)bgB*200 + s+1)*1024 + g*256 + jlane];
      }
      f32x4 ad = bcs;
      #pragma unroll
      for (int kk=0;kk<8;++kk){
        bf16x8 cf = *(const bf16x8*)&cbB[lb][kk*32 + quad*8];
        ad = MFMA(wdA[kk], cf, ad);
      }
      #pragma unroll
      for (int kk=0;kk<8;++kk){
        bf16x8 hf = *(const bf16x8*)&hbB[lb][kk*32 + quad*8];
        #pragma unroll
        for (int g=0; g<4; ++g) ag[g] = MFMA(wfA[g][kk], hf, ag[g]);
      }
      f32x4 hn;
      #pragma unroll
      for (int r=0;r<4;++r){
        float cs1 = tanhx(ad[r]);
        float cadj = cregB[r] + cs1*(tcurB - 1.0f);
        float fg = sigm(ag[0][r]);
        float ig = sigm(ag[1][r]);
        float og = sigm(ag[2][r]);
        float cg = sigm(ag[3][r]);
        float cn = fg*cadj + ig*cg;
        float hv = og*tanhx(cn);
        cregB[r]=cn; hn[r]=hv;
        hpB[r]=f2b(hv); cpB[r]=f2b(cn);
      }
      if (s < 199){
        tcurB = ts[(long long)bgB*200 + s+1];
        long long pw = ((((long long)(slot*16+grpB))*16 + lb)*64 + (jlane>>2))*3;
        u64 w0 = (u64)hpB[0] | ((u64)hpB[1]<<16) | ((u64)hpB[2]<<32) | (tag<<48);
        u64 w1 = (u64)hpB[3] | ((u64)cpB[0]<<16) | ((u64)cpB[1]<<32) | (tag<<48);
        u64 w2 = (u64)cpB[2] | ((u64)cpB[3]<<16) | (tag<<48);
        __hip_atomic_store(&pay[pw],   w0, __ATOMIC_RELAXED, __HIP_MEMORY_SCOPE_AGENT);
        __hip_atomic_store(&pay[pw+1], w1, __ATOMIC_RELAXED, __HIP_MEMORY_SCOPE_AGENT);
        __hip_atomic_store(&pay[pw+2], w2, __ATOMIC_RELAXED, __HIP_MEMORY_SCOPE_AGENT);
      }
      if (lstm==0){
        float e = hn[0]*wav[0] + hn[1]*wav[1] + hn[2]*wav[2] + hn[3]*wav[3];
        e += __shfl_xor(e, 16, 64);
        e += __shfl_xor(e, 32, 64);
        if (l < 16) atomicAdd(&E[(long long)bgB*256 + s], e);
      } else {
        *(us4*)&out2[((long long)bgB*200 + s)*256 + jlane] = hpB;
      }
    }
    // =========== exchange ===========
    if (s < 199){
      // B1: raw barrier -- step-s LDS reads all consumed via data deps;
      // publish stores continue draining in background.
      asm volatile("s_barrier" ::: "memory");
      // own chunks: registers -> LDS
      *(us4*)&hbA[lb][jlane] = hpA;
      *(us4*)&cbA[lb][jlane] = cpA;
      *(us4*)&hbB[lb][jlane] = hpB;
      *(us4*)&cbB[lb][jlane] = cpB;
      // sibling chunks: poll tagged words at MALL, unpack -> LDS (A then B;
      // B's flight hides under A's unpack)
      if (sibR){
        long long rbA = (((long long)(slot*16+grpA))*16 + bb)*192 + (long long)jj*12;
        long long rbB = (((long long)(slot*16+grpB))*16 + bb)*192 + (long long)jj*12;
        u64 W[12];
        for (;;){
          #pragma unroll
          for (int i=0;i<12;++i)
            W[i] = __hip_atomic_load(&pay[rbA+i], __ATOMIC_RELAXED, __HIP_MEMORY_SCOPE_AGENT);
          bool ok = true;
          #pragma unroll
          for (int i=0;i<12;++i) ok &= ((W[i]>>48) == tag);
          if (ok) break;
          __builtin_amdgcn_s_sleep(1);
        }
        #pragma unroll
        for (int i=0;i<4;++i){
          u64 w0=W[i*3], w1=W[i*3+1], w2=W[i*3+2];
          us4 hv, cv;
          hv[0]=(u16)w0; hv[1]=(u16)(w0>>16); hv[2]=(u16)(w0>>32); hv[3]=(u16)w1;
          cv[0]=(u16)(w1>>16); cv[1]=(u16)(w1>>32); cv[2]=(u16)w2; cv[3]=(u16)(w2>>16);
          *(us4*)&hbA[bb][jj*16+i*4] = hv;
          *(us4*)&cbA[bb][jj*16+i*4] = cv;
        }
        for (;;){
          #pragma unroll
          for (int i=0;i<12;++i)
            W[i] = __hip_atomic_load(&pay[rbB+i], __ATOMIC_RELAXED, __HIP_MEMORY_SCOPE_AGENT);
          bool ok = true;
          #pragma unroll
          for (int i=0;i<12;++i) ok &= ((W[i]>>48) == tag);
          if (ok) break;
          __builtin_amdgcn_s_sleep(1);
        }
        #pragma unroll
        for (int i=0;i<4;++i){
          u64 w0=W[i*3], w1=W[i*3+1], w2=W[i*3+2];
          us4 hv, cv;
          hv[0]=(u16)w0; hv[1]=(u16)(w0>>16); hv[2]=(u16)(w0>>32); hv[3]=(u16)w1;
          cv[0]=(u16)(w1>>16); cv[1]=(u16)(w1>>32); cv[2]=(u16)w2; cv[3]=(u16)(w2>>16);
          *(us4*)&hbB[bb][jj*16+i*4] = hv;
          *(us4*)&cbB[bb][jj*16+i*4] = cv;
        }
      }
      // B2: LDS writes visible to all waves
      asm volatile("s_waitcnt lgkmcnt(0)\n\ts_barrier" ::: "memory");
    }
  }
}

// ---------------- softmax over precomputed E -> alpha ----------------
__global__ __launch_bounds__(256) void k_attn(const float* __restrict__ E, float* __restrict__ alpha){
  __shared__ float buf[256];
  int b = blockIdx.x, tid = threadIdx.x;
  float Ev = (tid < 200) ? E[(long long)b*256 + tid] : -1e30f;
  buf[tid]=Ev; __syncthreads();
  for (int st=128; st>0; st>>=1){ if (tid<st) buf[tid]=fmaxf(buf[tid],buf[tid+st]); __syncthreads(); }
  float mx = buf[0]; __syncthreads();
  float e = (tid<200)? __expf(Ev-mx) : 0.f;
  buf[tid]=e; __syncthreads();
  for (int st=128; st>0; st>>=1){ if (tid<st) buf[tid]+=buf[tid+st]; __syncthreads(); }
  float sm = buf[0];
  if (tid<200) alpha[(long long)b*200+tid] = e/sm;
}

// ---------------- out = ctx @ Wout^T ----------------
__global__ __launch_bounds__(128) void k_out(const float* __restrict__ ctx, const float* __restrict__ Wout,
                                             float* __restrict__ out){
  __shared__ float cs[256];
  int b = blockIdx.x, t = threadIdx.x;
  cs[t] = ctx[b*256+t]; cs[t+128] = ctx[b*256+t+128];
  __syncthreads();
  const float* wr = Wout + (long long)t*256;
  float a0=0,a1=0,a2=0,a3=0;
  for (int j=0;j<256;j+=4){
    f32x4 v = *(const f32x4*)&wr[j];
    a0+=v[0]*cs[j]; a1+=v[1]*cs[j+1]; a2+=v[2]*cs[j+2]; a3+=v[3]*cs[j+3];
  }
  out[(long long)b*128 + t] = (a0+a1)+(a2+a3);
}

extern "C" void kernel_launch(void* const* d_in, const int* in_sizes, int n_in,
                              void* d_out, int out_size, void* d_ws, size_t ws_size,
                              hipStream_t stream)
{
  (void)in_sizes; (void)n_in; (void)out_size; (void)ws_size;
  const float* inputs = (const float*)d_in[0];
  const float* tstamp = (const float*)d_in[1];
  const float* emb    = (const float*)d_in[2];
  const float* Wall1w = (const float*)d_in[3];
  const float* Wall1b = (const float*)d_in[4];
  const float* Uall1w = (const float*)d_in[5];
  const float* Uall1b = (const float*)d_in[6];
  const float* Wd1w   = (const float*)d_in[7];
  const float* Wd1b   = (const float*)d_in[8];
  const float* Wall2w = (const float*)d_in[9];
  const float* Wall2b = (const float*)d_in[10];
  const float* Uall2w = (const float*)d_in[11];
  const float* Uall2b = (const float*)d_in[12];
  const float* Wd2w   = (const float*)d_in[13];
  const float* Wd2b   = (const float*)d_in[14];
  const float* wa     = (const float*)d_in[15];
  const float* Wbw    = (const float*)d_in[16];
  const float* Woutw  = (const float*)d_in[17];
  const float* h01    = (const float*)d_in[18];
  const float* c01    = (const float*)d_in[19];
  const float* h02    = (const float*)d_in[20];
  const float* c02    = (const float*)d_in[21];

  char* ws = (char*)d_ws;
  u16*   ux1   = (u16*)  (ws + 0);              // 52428800
  u16*   ux2   = (u16*)  (ws + 52428800LL);
  float* embF  = (float*)(ws + 104857600LL);    // 26214400
  u16*   embB  = (u16*)  (ws + 131072000LL);    // 13107200
  char*  scr   =          ws + 144179200LL;     // 72089600 region (A0 overlay)
  u16*   A0    = (u16*)scr;                     // 72089600 (dead after embed GEMM)
  u16*   out2  = (u16*)  (scr + 0);             // 13107200
  float* E     = (float*)(scr + 13107200LL);    // 131072 (stride-256 padded)
  float* ctx   = (float*)(scr + 13238272LL);    // 131072
  float* alpha = (float*)(scr + 13369344LL);    // 102400
  u64*   pay   = (u64*)  (scr + 13471744LL);    // 786432 (2 slots x 16 grp x 3072 u64)
  u16* embT    = (u16*)(ws + 216268800LL);      // 720896
  u16* Wall1B  = (u16*)(ws + 216989696LL);      // 524288
  u16* Wall2B  = (u16*)(ws + 217513984LL);
  u16* Uall1B  = (u16*)(ws + 218038272LL);
  u16* Uall2B  = (u16*)(ws + 218562560LL);
  u16* Wd1B    = (u16*)(ws + 219086848LL);      // 131072
  u16* Wd2B    = (u16*)(ws + 219217920LL);
  u16* WbB     = (u16*)(ws + 219348992LL);
  // total ws: ~219.5 MB

  // 1) all conversions (inputs, emb^T, 7 weights) in one launch
  k_prep<<<37824, 256, 0, stream>>>(inputs, A0, emb, embT,
                                    Wall1w, Wall2w, Uall1w, Uall2w, Wd1w, Wd2w, Wbw,
                                    Wall1B, Wall2B, Uall1B, Uall2B, Wd1B, Wd2B, WbB);
  // 2) embedded = inputs @ emb  (fp32 + bf16 copies)
  k_gemm<1><<<dim3(200,2), 256, 0, stream>>>(A0, embT, 256, 1408, embF, embB,
                                             nullptr, nullptr, nullptr, nullptr,
                                             nullptr, nullptr, nullptr, nullptr);
  // 3) ux1,ux2 = bf16( embedded @ Uall{1,2}^T + (Uall_b + Wall_b) ), one launch
  k_gemm<6><<<dim3(200,16), 256, 0, stream>>>(embB, Uall1B, 1024, 256, nullptr, ux1,
                                              Uall1b, Wall1b,
                                              Uall2B, ux2, Uall2b, Wall2b,
                                              nullptr, nullptr);
  // 4) zero E + ctx (atomic accumulation targets; after A0 is dead)
  k_init<<<256, 256, 0, stream>>>(E, ctx);
  // 5) both TimeLSTM scans (32 persistent WGs, 2-chunk pipelined exchange)
  k_scan<<<32, 256, 0, stream>>>(Wall1B, Wd1B, Wd1b, ux1, h01, c01,
                                 Wall2B, Wd2B, Wd2b, ux2, h02, c02,
                                 tstamp, wa, E, out2, pay);
  // 6) alpha = softmax(E)
  k_attn<<<128, 256, 0, stream>>>(E, alpha);
  // 7) ctx += sum_s emb * tanh(out2 @ Wb^T) * alpha  (fused, no P buffer)
  k_gemm<5><<<dim3(200,2), 256, 0, stream>>>(out2, WbB, 256, 256, ctx, nullptr,
                                             nullptr, nullptr, nullptr, nullptr,
                                             nullptr, nullptr, embF, alpha);
  // 8) out = ctx @ Wout^T
  k_out<<<128, 128, 0, stream>>>(ctx, Woutw, (float*)d_out);
}